// Round 12
// baseline (480.333 us; speedup 1.0000x reference)
//
#include <hip/hip_runtime.h>

#define GAT_N 50000
#define GAT_D 256
#define GAT_T 3
#define GAT_E 250000
#define GAT_B (GAT_T*GAT_N)      // 150000 (node,type) buckets
#define GAT_TOTE (GAT_T*GAT_E)   // 750000 edges total
#define GAT_COLS (GAT_T*GAT_D)   // 768 fused output columns
#define GAT_SLOPE 0.2f

typedef unsigned short u16;
typedef unsigned int u32;
typedef __attribute__((ext_vector_type(8))) short s16x8;     // raw bf16 storage
typedef __attribute__((ext_vector_type(8))) __bf16 bf16x8;   // MFMA operand
typedef __attribute__((ext_vector_type(4))) float f32x4;
typedef __attribute__((ext_vector_type(4))) u32 u32x4;

__device__ __forceinline__ u16 f2bf(float f) {
    u32 x = __builtin_bit_cast(u32, f);
    u32 r = (x + 0x7fffu + ((x >> 16) & 1u)) >> 16;   // RNE
    return (u16)r;
}
__device__ __forceinline__ float bf2f(u16 u) {
    u32 x = ((u32)u) << 16;
    return __builtin_bit_cast(float, x);
}
__device__ __forceinline__ float lo16(u32 w) {
    return __builtin_bit_cast(float, w << 16);
}
__device__ __forceinline__ float hi16(u32 w) {
    return __builtin_bit_cast(float, w & 0xffff0000u);
}

__global__ void gat_zero(u32* p, int n) {
    int i = blockIdx.x * 256 + threadIdx.x;
    if (i < n) p[i] = 0u;
}

// ---- fused prep: W1/W2 -> bf16 transposed, z -> bf16, cnt -> 0, bias3 ----
__global__ void gat_prep(const float* __restrict__ W1, const float* __restrict__ W2,
                         const float* __restrict__ z, const float* __restrict__ b1,
                         const float* __restrict__ b2, u16* __restrict__ WT1b,
                         u16* __restrict__ WT2b, u16* __restrict__ zb,
                         u32* __restrict__ cnt, float* __restrict__ bias3)
{
    int idx = blockIdx.x * 256 + threadIdx.x;
    if (idx < GAT_T * GAT_D * GAT_D) {               // 196608
        int t = idx >> 16, r = idx & 65535;
        int d = r >> 8, h = r & 255;
        WT1b[t * 65536 + h * 256 + d] = f2bf(W1[idx]);
        WT2b[t * 65536 + h * 256 + d] = f2bf(W2[idx]);
    }
    if (idx < GAT_B) cnt[idx] = 0u;
    if (idx < 2 * GAT_D) {
        const float* bb = (idx < GAT_D) ? b1 : b2;
        int c = idx & 255;
        bias3[idx] = bb[c] + bb[GAT_D + c] + bb[2 * GAT_D + c];
    }
    if (idx < GAT_N * GAT_D / 4) {
        f32x4 v = ((const f32x4*)z)[idx];
        ushort4 pk;
        pk.x = f2bf(v.x); pk.y = f2bf(v.y); pk.z = f2bf(v.z); pk.w = f2bf(v.w);
        ((ushort4*)zb)[idx] = pk;
    }
}

// ================= m97-style LDS-staged MFMA GEMM + fused attn dots =========
__global__ __launch_bounds__(256) void gat_gemm_tile(
    const u16* __restrict__ A, const u16* __restrict__ WTb,
    u16* __restrict__ H, const float* __restrict__ as_in,
    const float* __restrict__ ad_in, float* __restrict__ a_srcA,
    float* __restrict__ a_dstA)
{
    __shared__ u16 Als[128 * 64];   // 16 KB
    __shared__ u16 Bls[128 * 64];   // 16 KB
    int tid  = threadIdx.x;
    int wave = tid >> 6, lane = tid & 63;
    int quad = lane >> 4, l16 = lane & 15;
    int wm = wave & 1, wn = wave >> 1;
    int lrow = lane >> 3;
    int lk   = (lane & 7) * 8;

    size_t arow0 = (size_t)blockIdx.x * 128;
    size_t brow0 = (size_t)blockIdx.y * 128;

    f32x4 acc[4][4] = {};

    for (int ks = 0; ks < 4; ++ks) {
        int k0 = ks * 64;
        #pragma unroll
        for (int r = 0; r < 4; ++r) {
            int srow = r * 32 + wave * 8 + lrow;
            const u16* gA = A   + (arow0 + srow) * GAT_D + k0 + lk;
            const u16* gB = WTb + (brow0 + srow) * GAT_D + k0 + lk;
            u16* lA = Als + r * 2048 + wave * 512;
            u16* lB = Bls + r * 2048 + wave * 512;
#if defined(__has_builtin) && __has_builtin(__builtin_amdgcn_global_load_lds)
            __builtin_amdgcn_global_load_lds(
                (const __attribute__((address_space(1))) void*)gA,
                (__attribute__((address_space(3))) void*)lA, 16, 0, 0);
            __builtin_amdgcn_global_load_lds(
                (const __attribute__((address_space(1))) void*)gB,
                (__attribute__((address_space(3))) void*)lB, 16, 0, 0);
#else
            *(s16x8*)(lA + lane * 8) = *(const s16x8*)gA;
            *(s16x8*)(lB + lane * 8) = *(const s16x8*)gB;
#endif
        }
        __syncthreads();

        #pragma unroll
        for (int kk = 0; kk < 2; ++kk) {
            bf16x8 af[4], bf[4];
            #pragma unroll
            for (int i = 0; i < 4; ++i) {
                af[i] = __builtin_bit_cast(bf16x8,
                    *(const s16x8*)(Als + (wm * 64 + i * 16 + l16) * 64 + kk * 32 + quad * 8));
                bf[i] = __builtin_bit_cast(bf16x8,
                    *(const s16x8*)(Bls + (wn * 64 + i * 16 + l16) * 64 + kk * 32 + quad * 8));
            }
            #pragma unroll
            for (int i = 0; i < 4; ++i)
                #pragma unroll
                for (int j = 0; j < 4; ++j)
                    acc[i][j] = __builtin_amdgcn_mfma_f32_16x16x32_bf16(
                        af[i], bf[j], acc[i][j], 0, 0, 0);
        }
        __syncthreads();
    }

    int gcol0 = blockIdx.y * 128 + wn * 64;
    int t   = gcol0 >> 8;
    int ch0 = gcol0 & 255;
    u16* Ht = H + (size_t)t * GAT_N * GAT_D;
    int rowb = blockIdx.x * 128 + wm * 64 + quad * 4;
    #pragma unroll
    for (int i = 0; i < 4; ++i) {
        #pragma unroll
        for (int j = 0; j < 4; ++j) {
            int ch = ch0 + j * 16 + l16;
            #pragma unroll
            for (int r = 0; r < 4; ++r) {
                int row = rowb + i * 16 + r;
                if (row < GAT_N) Ht[(size_t)row * GAT_D + ch] = f2bf(acc[i][j][r]);
            }
        }
    }

    // ---- fused attn partial dots: a_src/a_dst += acc . as/ad over my cols --
    float asv[4], adv[4];
    #pragma unroll
    for (int j = 0; j < 4; ++j) {
        int ch = ch0 + j * 16 + l16;
        asv[j] = as_in[t * GAT_D + ch];
        adv[j] = ad_in[t * GAT_D + ch];
    }
    #pragma unroll
    for (int i = 0; i < 4; ++i) {
        float ps[4] = {}, pd[4] = {};
        #pragma unroll
        for (int j = 0; j < 4; ++j) {
            f32x4 a = acc[i][j];
            #pragma unroll
            for (int r = 0; r < 4; ++r) {
                ps[r] += a[r] * asv[j];
                pd[r] += a[r] * adv[j];
            }
        }
        #pragma unroll
        for (int d = 1; d < 16; d <<= 1) {
            #pragma unroll
            for (int r = 0; r < 4; ++r) {
                ps[r] += __shfl_xor(ps[r], d);
                pd[r] += __shfl_xor(pd[r], d);
            }
        }
        if (l16 == 0) {
            int row = rowb + i * 16;
            #pragma unroll
            for (int r = 0; r < 4; ++r) {
                if (row + r < GAT_N) {
                    atomicAdd(a_srcA + t * GAT_N + row + r, ps[r]);
                    atomicAdd(a_dstA + t * GAT_N + row + r, pd[r]);
                }
            }
        }
    }
}

// ================= CSR build (bucket g = dst*3 + t) =================
__global__ void gat_hist(const int* __restrict__ ei, u32* __restrict__ cnt) {
    int idx = blockIdx.x * 256 + threadIdx.x;
    if (idx >= GAT_TOTE) return;
    int t = idx / GAT_E;
    int e = idx - t * GAT_E;
    int dst = ei[t * 2 * GAT_E + GAT_E + e];
    atomicAdd(&cnt[dst * GAT_T + t], 1u);
}

__global__ __launch_bounds__(256) void gat_scan_a(
    const u32* __restrict__ cnt, u32* __restrict__ off, u32* __restrict__ bsum)
{
    __shared__ u32 s[256];
    int tid = threadIdx.x;
    int idx = blockIdx.x * 256 + tid;
    u32 v = (idx < GAT_B) ? cnt[idx] : 0u;
    s[tid] = v; __syncthreads();
    for (int d = 1; d < 256; d <<= 1) {
        u32 t = (tid >= d) ? s[tid - d] : 0u;
        __syncthreads();
        s[tid] += t;
        __syncthreads();
    }
    if (idx < GAT_B) off[idx] = s[tid] - v;
    if (tid == 255) bsum[blockIdx.x] = s[255];
}

__global__ __launch_bounds__(1024) void gat_scan_b(u32* bsum, int nb) {
    __shared__ u32 s[1024];
    int tid = threadIdx.x;
    u32 v = (tid < nb) ? bsum[tid] : 0u;
    s[tid] = v; __syncthreads();
    for (int d = 1; d < 1024; d <<= 1) {
        u32 t = (tid >= d) ? s[tid - d] : 0u;
        __syncthreads();
        s[tid] += t;
        __syncthreads();
    }
    if (tid < nb) bsum[tid] = s[tid] - v;
}

__global__ void gat_scan_c(u32* off, const u32* __restrict__ bsum, u32* cnt) {
    int idx = blockIdx.x * 256 + threadIdx.x;
    if (idx < GAT_B) { off[idx] += bsum[blockIdx.x]; cnt[idx] = 0u; }
}

// psrc stores ABSOLUTE H row (t*N+src)
__global__ void gat_scatter(const int* __restrict__ ei,
                            const u32* __restrict__ off, u32* cur,
                            int* __restrict__ psrc)
{
    int idx = blockIdx.x * 256 + threadIdx.x;
    if (idx >= GAT_TOTE) return;
    int t = idx / GAT_E;
    int e = idx - t * GAT_E;
    int src = ei[t * 2 * GAT_E + e];
    int dst = ei[t * 2 * GAT_E + GAT_E + e];
    int g = dst * GAT_T + t;
    u32 pos = off[g] + atomicAdd(&cur[g], 1u);
    psrc[pos] = t * GAT_N + src;
}

// ================= alpha pre-pass: one thread per (node,type) ===============
__global__ void gat_alpha(const u32* __restrict__ off, const int* __restrict__ psrc,
                          const float* __restrict__ a_srcA,
                          const float* __restrict__ a_dstA,
                          float* __restrict__ alphaf)
{
    int g = blockIdx.x * 256 + threadIdx.x;
    if (g >= GAT_B) return;
    u32 o0 = off[g];
    u32 o1 = (g + 1 < GAT_B) ? off[g + 1] : (u32)GAT_TOTE;
    if (o1 == o0) return;
    int n = g / GAT_T, t = g - n * GAT_T;
    float adn = a_dstA[t * GAT_N + n];
    float m = -1e30f;
    for (u32 k = o0; k < o1; ++k) {
        float e = a_srcA[psrc[k]] + adn;
        e = (e > 0.f) ? e : GAT_SLOPE * e;
        m = fmaxf(m, e);
    }
    float den = 0.f;
    for (u32 k = o0; k < o1; ++k) {
        float e = a_srcA[psrc[k]] + adn;
        e = (e > 0.f) ? e : GAT_SLOPE * e;
        float a = expf(e - m);
        alphaf[k] = a;
        den += a;
    }
    float rd = 1.0f / den;
    for (u32 k = o0; k < o1; ++k) alphaf[k] *= rd;
}

// ================= streaming gather: one wave per node ======================
// flat loop over the node's 3 contiguous type-segments; 2 edges/iter.
__global__ __launch_bounds__(64) void gat_gather(
    const u32* __restrict__ off, const int* __restrict__ psrc,
    const float* __restrict__ alphaf, const u16* __restrict__ Hfb,
    const float* __restrict__ bias3, const float* __restrict__ Wh,
    const float* __restrict__ bh, int layer, u16* __restrict__ x2b,
    float* __restrict__ out)
{
    int n = blockIdx.x;
    int lane = threadIdx.x;
    int half = lane >> 5, l32 = lane & 31;
    u32 o0 = off[n * GAT_T];
    u32 o1 = (n * GAT_T + GAT_T < GAT_B) ? off[n * GAT_T + GAT_T] : (u32)GAT_TOTE;
    float r[8] = {};
    const u16* Hbase = Hfb + l32 * 8;

    for (u32 k = o0; k < o1; k += 2) {
        u32 kk = k + half;
        if (kk < o1) {
            float alpha = alphaf[kk];
            int rs = psrc[kk];
            u32x4 w = __builtin_bit_cast(u32x4,
                *(const s16x8*)(Hbase + (size_t)rs * GAT_D));
            r[0] += alpha * lo16(w.x); r[1] += alpha * hi16(w.x);
            r[2] += alpha * lo16(w.y); r[3] += alpha * hi16(w.y);
            r[4] += alpha * lo16(w.z); r[5] += alpha * hi16(w.z);
            r[6] += alpha * lo16(w.w); r[7] += alpha * hi16(w.w);
        }
    }
    #pragma unroll
    for (int i = 0; i < 8; ++i) r[i] += __shfl_xor(r[i], 32);

    int c0 = l32 * 8;
    const float* b3 = bias3 + layer * GAT_D;
    float v[8];
    #pragma unroll
    for (int i = 0; i < 8; ++i) v[i] = fmaxf(r[i] + b3[c0 + i], 0.f);

    if (layer == 0) {
        if (half == 0) {
            u16 pk[8];
            #pragma unroll
            for (int i = 0; i < 8; ++i) pk[i] = f2bf(v[i]);
            *(s16x8*)(x2b + (size_t)n * GAT_D + c0) = *(s16x8*)pk;
        }
    } else {
        float wsum = 0.f;
        #pragma unroll
        for (int i = 0; i < 8; ++i) wsum += v[i] * Wh[c0 + i];
        #pragma unroll
        for (int d = 1; d < 32; d <<= 1) wsum += __shfl_xor(wsum, d);
        if (lane == 0) out[n] = 1.0f / (1.0f + expf(-(wsum + bh[0])));
    }
}

// retain harness-expected symbol
__global__ void PyGTypeSpecificGAT_80075370266775_kernel() {}

extern "C" void kernel_launch(void* const* d_in, const int* in_sizes, int n_in,
                              void* d_out, int out_size, void* d_ws, size_t ws_size,
                              hipStream_t stream)
{
    (void)in_sizes; (void)n_in; (void)out_size; (void)ws_size;
    const float* z   = (const float*)d_in[0];
    const int*   ei  = (const int*)d_in[1];
    const float* W1  = (const float*)d_in[2];
    const float* as1 = (const float*)d_in[3];
    const float* ad1 = (const float*)d_in[4];
    const float* b1  = (const float*)d_in[5];
    const float* W2  = (const float*)d_in[6];
    const float* as2 = (const float*)d_in[7];
    const float* ad2 = (const float*)d_in[8];
    const float* b2  = (const float*)d_in[9];
    const float* Wh  = (const float*)d_in[10];
    const float* bh  = (const float*)d_in[11];
    float* out = (float*)d_out;

    // ---- workspace (~137 MB; ≥156 MB proven). zb/x2b must not be last
    // (gemm staging over-reads ≤24 KB past row 50000).
    char* p = (char*)d_ws;
    u16*  Hfb  = (u16*)p;  p += (size_t)GAT_T * GAT_N * GAT_D * 2;  // 76.8 MB
    u16*  x2b  = (u16*)p;  p += (size_t)GAT_N * GAT_D * 2;          // 25.6 MB
    u16*  zb   = (u16*)p;  p += (size_t)GAT_N * GAT_D * 2;          // 25.6 MB
    float* a_srcA = (float*)p; p += (size_t)GAT_B * 4;              // contiguous
    float* a_dstA = (float*)p; p += (size_t)GAT_B * 4;              //  with prev
    u32*  off  = (u32*)p;  p += (size_t)GAT_B * 4;
    u32*  cnt  = (u32*)p;  p += (size_t)GAT_B * 4;                  // also cursor
    u32*  bsum = (u32*)p;  p += 1024 * 4;
    int*  psrc = (int*)p;  p += (size_t)GAT_TOTE * 4;               // 3 MB
    float* alphaf = (float*)p; p += (size_t)GAT_TOTE * 4;           // 3 MB
    u16*  WT1b = (u16*)p;  p += (size_t)GAT_COLS * GAT_D * 2;
    u16*  WT2b = (u16*)p;  p += (size_t)GAT_COLS * GAT_D * 2;
    float* bias3 = (float*)p; p += 2 * GAT_D * 4;

    const int SCAN_BLKS = (GAT_B + 255) / 256;              // 586
    const int EDGE_BLKS = (GAT_TOTE + 255) / 256;           // 2930
    const int PREP_BLKS = (GAT_N * GAT_D / 4 + 255) / 256;  // 12500

    gat_prep<<<PREP_BLKS, 256, 0, stream>>>(W1, W2, z, b1, b2, WT1b, WT2b,
                                            zb, cnt, bias3);
    gat_hist<<<EDGE_BLKS, 256, 0, stream>>>(ei, cnt);
    gat_scan_a<<<SCAN_BLKS, 256, 0, stream>>>(cnt, off, bsum);
    gat_scan_b<<<1, 1024, 0, stream>>>(bsum, SCAN_BLKS);
    gat_scan_c<<<SCAN_BLKS, 256, 0, stream>>>(off, bsum, cnt);
    gat_scatter<<<EDGE_BLKS, 256, 0, stream>>>(ei, off, cnt, psrc);

    dim3 ggemm((GAT_N + 127) / 128, GAT_COLS / 128);   // (391, 6)

    for (int layer = 0; layer < 2; ++layer) {
        const u16*   A   = (layer == 0) ? zb   : x2b;
        const u16*   WTb = (layer == 0) ? WT1b : WT2b;
        const float* as_ = (layer == 0) ? as1  : as2;
        const float* ad_ = (layer == 0) ? ad1  : ad2;

        gat_zero<<<(2 * GAT_B + 255) / 256, 256, 0, stream>>>(
            (u32*)a_srcA, 2 * GAT_B);
        gat_gemm_tile<<<ggemm, 256, 0, stream>>>(A, WTb, Hfb, as_, ad_,
                                                 a_srcA, a_dstA);
        gat_alpha<<<SCAN_BLKS, 256, 0, stream>>>(off, psrc, a_srcA, a_dstA,
                                                 alphaf);
        gat_gather<<<GAT_N, 64, 0, stream>>>(off, psrc, alphaf, Hfb, bias3,
                                             Wh, bh, layer, x2b, out);
    }
}